// Round 5
// baseline (4000.001 us; speedup 1.0000x reference)
//
#include <hip/hip_runtime.h>

constexpr int NTOK  = 16 * 4096;  // 65536 tokens
constexpr int KSEL  = 256;        // top-k = 2*CDIM
constexpr int UCAP  = 8192;       // sidecar chunk size (fp64 scratch rows)
constexpr int NCHNK = 2;          // sidecar chunks
constexpr int UCAPT = UCAP * NCHNK;

using short8 = __attribute__((ext_vector_type(8))) short;
using ush4   = __attribute__((ext_vector_type(4))) unsigned short;
using f32x4  = __attribute__((ext_vector_type(4))) float;

__device__ inline unsigned short bf16_rne(float x) {
    unsigned u = __float_as_uint(x);
    unsigned r = u + 0x7fffu + ((u >> 16) & 1u);
    return (unsigned short)(r >> 16);
}
__device__ inline float bf16_f32(unsigned short h) {
    return __uint_as_float((unsigned)h << 16);
}

// ---------------------------------------------------------------------------
// Weight split+transpose: W[K][M] fp32 -> WhT/WlT [M][K] bf16 (hi + lo).
// ---------------------------------------------------------------------------
__global__ __launch_bounds__(256)
void wsplit_t(const float* __restrict__ W, unsigned short* __restrict__ WhT,
              unsigned short* __restrict__ WlT, int K, int M)
{
    __shared__ float tile[32][33];
    const int tid = threadIdx.x;
    const int tx = tid & 31, ty = tid >> 5;          // ty 0..7
    const int m0 = blockIdx.x * 32, k0 = blockIdx.y * 32;
#pragma unroll
    for (int i = 0; i < 4; ++i)
        tile[ty + 8 * i][tx] = W[(size_t)(k0 + ty + 8 * i) * M + m0 + tx];
    __syncthreads();
#pragma unroll
    for (int i = 0; i < 4; ++i) {
        int m = ty + 8 * i;
        float v = tile[tx][m];
        unsigned short hh = bf16_rne(v);
        unsigned short ll = bf16_rne(v - bf16_f32(hh));
        WhT[(size_t)(m0 + m) * K + k0 + tx] = hh;
        WlT[(size_t)(m0 + m) * K + k0 + tx] = ll;
    }
}

// ---------------------------------------------------------------------------
// Unified split-bf16 MFMA GEMM: C = act(A@W + b), 3 products (hh+lh+hl).
// A_SPLIT=1: A is interleaved bf16 pair [rows][2K] (hi at +0, lo at +K).
// A_SPLIT=0: A is f32 [rows][K], split on the fly (layer-1 only).
// OUT_SPLIT=1: C is interleaved bf16 pair [rows][2M]; else f32 [rows][M].
// mask (optional, f32 [rows][M]): zero where mask>0 (encoder L4).
// k-loop body / LDS layout / fragment mapping identical to the proven R2
// gemm_mfma.
// ---------------------------------------------------------------------------
template<int K, int RELU, int OUT_SPLIT, int A_SPLIT>
__global__ __launch_bounds__(256)
void gemm_u(const void* Ap, const unsigned short* __restrict__ WhT,
            const unsigned short* __restrict__ WlT, const float* __restrict__ bias,
            void* Cp, int M, const float* __restrict__ mask)
{
    __shared__ __align__(16) unsigned short sAh[128 * 40];
    __shared__ __align__(16) unsigned short sAl[128 * 40];
    __shared__ __align__(16) unsigned short sBh[128 * 40];
    __shared__ __align__(16) unsigned short sBl[128 * 40];

    const int tid = threadIdx.x;
    const int lane = tid & 63, wid = tid >> 6;
    const int quad = lane >> 4, l16 = lane & 15;

    // XCD-aware swizzle (nwg % 8 == 0 for all launches here)
    const int gridX = gridDim.x;
    int nwg = gridX * gridDim.y;
    int bid = blockIdx.y * gridX + blockIdx.x;
    int cpx = nwg >> 3;
    int swz = (bid & 7) * cpx + (bid >> 3);
    const int rowBase = (swz / gridX) * 128;
    const int colBase = (swz % gridX) * 128;

    const int wr = (wid & 1) * 64, wc = (wid >> 1) * 64;
    const int sr = tid >> 1;          // staging row/col 0..127
    const int sk = (tid & 1) * 16;    // staging k offset 0/16

    f32x4 acc[4][4];
#pragma unroll
    for (int i = 0; i < 4; ++i)
#pragma unroll
        for (int j = 0; j < 4; ++j)
            acc[i][j] = (f32x4){0.f, 0.f, 0.f, 0.f};

    for (int k0 = 0; k0 < K; k0 += 32) {
        short8 Ah0, Ah1, Al0, Al1;
        if constexpr (A_SPLIT) {
            const unsigned short* Au = (const unsigned short*)Ap;
            size_t base = (size_t)(rowBase + sr) * (2 * K) + k0 + sk;
            Ah0 = *(const short8*)&Au[base];
            Ah1 = *(const short8*)&Au[base + 8];
            Al0 = *(const short8*)&Au[base + K];
            Al1 = *(const short8*)&Au[base + K + 8];
        } else {
            const float* Af = (const float*)Ap;
            const float* ap = &Af[(size_t)(rowBase + sr) * K + k0 + sk];
            float4 a0 = *(const float4*)ap;
            float4 a1 = *(const float4*)(ap + 4);
            float4 a2 = *(const float4*)(ap + 8);
            float4 a3 = *(const float4*)(ap + 12);
            float f[16] = {a0.x, a0.y, a0.z, a0.w, a1.x, a1.y, a1.z, a1.w,
                           a2.x, a2.y, a2.z, a2.w, a3.x, a3.y, a3.z, a3.w};
            unsigned short __align__(16) hs[16], ls[16];
#pragma unroll
            for (int j = 0; j < 16; ++j) {
                hs[j] = bf16_rne(f[j]);
                ls[j] = bf16_rne(f[j] - bf16_f32(hs[j]));
            }
            Ah0 = *(short8*)&hs[0]; Ah1 = *(short8*)&hs[8];
            Al0 = *(short8*)&ls[0]; Al1 = *(short8*)&ls[8];
        }
        const unsigned short* whp = &WhT[(size_t)(colBase + sr) * K + k0 + sk];
        const unsigned short* wlp = &WlT[(size_t)(colBase + sr) * K + k0 + sk];
        short8 wh0 = *(const short8*)whp;
        short8 wh1 = *(const short8*)(whp + 8);
        short8 wl0 = *(const short8*)wlp;
        short8 wl1 = *(const short8*)(wlp + 8);

        __syncthreads();
        *(short8*)&sAh[sr * 40 + sk]     = Ah0;
        *(short8*)&sAh[sr * 40 + sk + 8] = Ah1;
        *(short8*)&sAl[sr * 40 + sk]     = Al0;
        *(short8*)&sAl[sr * 40 + sk + 8] = Al1;
        *(short8*)&sBh[sr * 40 + sk]     = wh0;
        *(short8*)&sBh[sr * 40 + sk + 8] = wh1;
        *(short8*)&sBl[sr * 40 + sk]     = wl0;
        *(short8*)&sBl[sr * 40 + sk + 8] = wl1;
        __syncthreads();

        short8 ah[4], al[4], bh[4], bl[4];
#pragma unroll
        for (int t4 = 0; t4 < 4; ++t4) {
            ah[t4] = *(const short8*)&sAh[(wr + t4 * 16 + l16) * 40 + quad * 8];
            al[t4] = *(const short8*)&sAl[(wr + t4 * 16 + l16) * 40 + quad * 8];
            bh[t4] = *(const short8*)&sBh[(wc + t4 * 16 + l16) * 40 + quad * 8];
            bl[t4] = *(const short8*)&sBl[(wc + t4 * 16 + l16) * 40 + quad * 8];
        }
#pragma unroll
        for (int rt = 0; rt < 4; ++rt)
#pragma unroll
            for (int ct = 0; ct < 4; ++ct) {
                acc[rt][ct] = __builtin_amdgcn_mfma_f32_16x16x32_bf16(ah[rt], bh[ct], acc[rt][ct], 0, 0, 0);
                acc[rt][ct] = __builtin_amdgcn_mfma_f32_16x16x32_bf16(al[rt], bh[ct], acc[rt][ct], 0, 0, 0);
                acc[rt][ct] = __builtin_amdgcn_mfma_f32_16x16x32_bf16(ah[rt], bl[ct], acc[rt][ct], 0, 0, 0);
            }
    }

#pragma unroll
    for (int ct = 0; ct < 4; ++ct) {
        int col = colBase + wc + ct * 16 + l16;
        float bc = bias[col];
#pragma unroll
        for (int rt = 0; rt < 4; ++rt)
#pragma unroll
            for (int r = 0; r < 4; ++r) {
                int row = rowBase + wr + rt * 16 + quad * 4 + r;
                float v = acc[rt][ct][r] + bc;
                if (RELU) v = fmaxf(v, 0.f);
                if (mask) { if (mask[(size_t)row * M + col] > 0.f) v = 0.f; }
                if constexpr (OUT_SPLIT) {
                    unsigned short* Cs = (unsigned short*)Cp;
                    unsigned short hh = bf16_rne(v);
                    unsigned short ll = bf16_rne(v - bf16_f32(hh));
                    Cs[(size_t)row * (2 * M) + col]     = hh;
                    Cs[(size_t)row * (2 * M) + M + col] = ll;
                } else {
                    ((float*)Cp)[(size_t)row * M + col] = v;
                }
            }
    }
}

// ---------------------------------------------------------------------------
// Pass-1 topk: exact-k radix select on f32 energies + boundary-gap
// detection (uncertain tokens -> meta for fp64 redo). Reads f32 h, rewrites
// in place as interleaved bf16 hi/lo pair [t][2048]. Each block touches only
// its own 4 KiB row -> in-place safe.
// ---------------------------------------------------------------------------
__global__ __launch_bounds__(256)
void topk_pass1(const float* h, unsigned short* hsplit, int* __restrict__ meta)
{
    const int t = blockIdx.x, tid = threadIdx.x;
    const int lane = tid & 63, wid = tid >> 6;

    __shared__ unsigned hist[256];
    __shared__ unsigned wsum[4];
    __shared__ unsigned dmx[4];
    __shared__ unsigned s_prefix;
    __shared__ int s_need;

    float4 hv = ((const float4*)(h + (size_t)t * 1024))[tid];
    float v[4] = {hv.x, hv.y, hv.z, hv.w};
    unsigned u[4];
#pragma unroll
    for (int j = 0; j < 4; ++j) u[j] = __float_as_uint(v[j] * v[j]);

    if (tid == 0) { s_prefix = 0u; s_need = KSEL; }
    __syncthreads();

    for (int p = 3; p >= 0; --p) {
        unsigned pref = s_prefix;       // stable: trailing barrier of prev pass
        int need = s_need;
        hist[tid] = 0u;
        __syncthreads();
#pragma unroll
        for (int j = 0; j < 4; ++j) {
            bool match = (p == 3) || ((u[j] >> (8 * (p + 1))) == (pref >> (8 * (p + 1))));
            if (match) atomicAdd(&hist[(u[j] >> (8 * p)) & 255u], 1u);
        }
        __syncthreads();
        unsigned x = hist[tid];
        unsigned s = x;                 // inclusive suffix within wave
#pragma unroll
        for (int off = 1; off < 64; off <<= 1) {
            unsigned o = __shfl_down(s, off);
            if (lane + off < 64) s += o;
        }
        if (lane == 0) wsum[wid] = s;
        __syncthreads();
        unsigned above = 0;
        for (int w = wid + 1; w < 4; ++w) above += wsum[w];
        unsigned incl = s + above;
        unsigned excl = incl - x;
        if (incl >= (unsigned)need && excl < (unsigned)need) {
            s_prefix = pref | ((unsigned)tid << (8 * p));
            s_need = need - (int)excl;
        }
        __syncthreads();
    }
    const unsigned tau = s_prefix;

    unsigned cg = 0, ce = 0;
#pragma unroll
    for (int j = 0; j < 4; ++j) {
        cg += (u[j] > tau) ? 1u : 0u;
        ce += (u[j] == tau) ? 1u : 0u;
    }
    unsigned packed = (cg << 16) | ce;
    unsigned ps = packed;               // inclusive prefix within wave
#pragma unroll
    for (int off = 1; off < 64; off <<= 1) {
        unsigned o = __shfl_up(ps, off);
        if (lane >= off) ps += o;
    }
    if (lane == 63) wsum[wid] = ps;
    __syncthreads();
    unsigned below = 0;
    for (int w = 0; w < wid; ++w) below += wsum[w];
    unsigned total = wsum[0] + wsum[1] + wsum[2] + wsum[3];
    unsigned incl = ps + below;
    int need_eq = KSEL - (int)(total >> 16);
    int eq_base = (int)((incl - packed) & 0xffffu);

    bool kp[4];
    {
        int r = 0;
#pragma unroll
        for (int j = 0; j < 4; ++j) {
            if (u[j] > tau) kp[j] = true;
            else if (u[j] == tau) { kp[j] = (eq_base + r) < need_eq; ++r; }
            else kp[j] = false;
        }
    }

    // max dropped energy (bit patterns of non-negative floats order correctly)
    unsigned dmax = 0;
#pragma unroll
    for (int j = 0; j < 4; ++j) if (!kp[j] && u[j] > dmax) dmax = u[j];
#pragma unroll
    for (int off = 32; off > 0; off >>= 1) {
        unsigned o = __shfl_xor(dmax, off);
        if (o > dmax) dmax = o;
    }
    if (lane == 0) dmx[wid] = dmax;
    __syncthreads();
    if (tid == 0) {
        unsigned lo = dmx[0];
        for (int w = 1; w < 4; ++w) if (dmx[w] > lo) lo = dmx[w];
        float tauf = __uint_as_float(tau);
        float lof  = __uint_as_float(lo);
        // margin covers split-bf16 MFMA encoder error (dh_max ~6e-5, ~6x slack)
        if (tauf - lof <= fmaf(tauf, 4e-4f, 4e-5f)) {
            int slot = atomicAdd(&meta[0], 1);
            if (slot < UCAPT) meta[1 + slot] = t;
        }
    }

    unsigned short hs[4], ls[4];
#pragma unroll
    for (int j = 0; j < 4; ++j) {
        float ov = kp[j] ? v[j] : 0.f;
        hs[j] = bf16_rne(ov);
        ls[j] = bf16_rne(ov - bf16_f32(hs[j]));
    }
    size_t base = (size_t)t * 2048 + 4 * tid;
    *(ush4*)&hsplit[base]        = (ush4){hs[0], hs[1], hs[2], hs[3]};
    *(ush4*)&hsplit[base + 1024] = (ush4){ls[0], ls[1], ls[2], ls[3]};
}

// ---------------------------------------------------------------------------
// fp64 sidecar (chunked): gather x rows for uncertain tokens of one chunk.
// ---------------------------------------------------------------------------
__global__ __launch_bounds__(256)
void gather_x(const float* __restrict__ x, double* __restrict__ a64,
              const int* __restrict__ meta, int chunk)
{
    int cnt = meta[0]; if (cnt > UCAPT) cnt = UCAPT;
    int g = chunk * UCAP + blockIdx.x;
    if (g >= cnt) return;
    int tok = meta[1 + g];
    const float* src = &x[(size_t)tok * 512];
    double* dst = &a64[(size_t)blockIdx.x * 512];
    for (int i = threadIdx.x; i < 512; i += 256) dst[i] = (double)src[i];
}

// ---------------------------------------------------------------------------
// fp64 GEMM over one sidecar chunk. 64x64 tile, 256 threads, 4x4/thr.
// ---------------------------------------------------------------------------
template<int K, int RELU, int MASKED>
__global__ __launch_bounds__(256)
void gemm_f64(const double* __restrict__ A, const float* __restrict__ W,
              const float* __restrict__ bias, double* __restrict__ Cd,
              int M, const int* __restrict__ meta, const float* __restrict__ mp,
              int chunk)
{
    int cnt = meta[0]; if (cnt > UCAPT) cnt = UCAPT;
    int cloc = cnt - chunk * UCAP;
    if (cloc < 0) cloc = 0; if (cloc > UCAP) cloc = UCAP;
    const int rowBase = blockIdx.y * 64;
    if (rowBase >= cloc) return;
    const int colBase = blockIdx.x * 64;

    __shared__ double sA[16][65];
    __shared__ double sW[16][65];
    const int tid = threadIdx.x;
    const int tx = tid & 15, ty = tid >> 4;
    const int lr = tid & 63;            // A row 0..63
    const int lk4 = (tid >> 6) * 4;     // A k offset 0/4/8/12
    const int wk = tid >> 4;            // W k row 0..15
    const int wc = (tid & 15) * 4;      // W col offset

    double acc[4][4] = {};

    for (int k0 = 0; k0 < K; k0 += 16) {
        const double* ap = &A[(size_t)(rowBase + lr) * K + k0 + lk4];
        double a0 = ap[0], a1 = ap[1], a2 = ap[2], a3 = ap[3];
        float4 wv = *(const float4*)&W[(size_t)(k0 + wk) * M + colBase + wc];
        __syncthreads();
        sA[lk4 + 0][lr] = a0; sA[lk4 + 1][lr] = a1;
        sA[lk4 + 2][lr] = a2; sA[lk4 + 3][lr] = a3;
        sW[wk][wc + 0] = (double)wv.x; sW[wk][wc + 1] = (double)wv.y;
        sW[wk][wc + 2] = (double)wv.z; sW[wk][wc + 3] = (double)wv.w;
        __syncthreads();
#pragma unroll
        for (int k = 0; k < 16; ++k) {
            double av[4], wl[4];
#pragma unroll
            for (int i = 0; i < 4; ++i) av[i] = sA[k][ty * 4 + i];
#pragma unroll
            for (int i = 0; i < 4; ++i) wl[i] = sW[k][tx * 4 + i];
#pragma unroll
            for (int a = 0; a < 4; ++a)
#pragma unroll
                for (int b = 0; b < 4; ++b)
                    acc[a][b] = fma(av[a], wl[b], acc[a][b]);
        }
    }

#pragma unroll
    for (int a = 0; a < 4; ++a) {
        int row = rowBase + ty * 4 + a;
        if (row >= cloc) continue;
        int tok = MASKED ? meta[1 + chunk * UCAP + row] : 0;
#pragma unroll
        for (int b = 0; b < 4; ++b) {
            int col = colBase + tx * 4 + b;
            double vv = acc[a][b] + (double)bias[col];
            if (RELU) vv = vv > 0.0 ? vv : 0.0;
            if (MASKED) { if (mp[(size_t)tok * 1024 + col] > 0.f) vv = 0.0; }
            Cd[(size_t)row * M + col] = vv;
        }
    }
}

// ---------------------------------------------------------------------------
// Pass-2 topk for uncertain tokens of one chunk: exact fp64 energies,
// bitonic sort (energy desc, idx asc), keep ranks < 256; scatter masked
// interleaved bf16 hi/lo rows into hsplit.
// ---------------------------------------------------------------------------
__global__ __launch_bounds__(256)
void topk_pass2(const double* __restrict__ h64, unsigned short* __restrict__ hsplit,
                const int* __restrict__ meta, int chunk)
{
    int cnt = meta[0]; if (cnt > UCAPT) cnt = UCAPT;
    int g = chunk * UCAP + blockIdx.x;
    if (g >= cnt) return;
    int tok = meta[1 + g];

    __shared__ double se[1024];
    __shared__ unsigned short si[1024];
    __shared__ unsigned char keep[1024];
    const int tid = threadIdx.x;
    const double* row = &h64[(size_t)blockIdx.x * 1024];

#pragma unroll
    for (int t = 0; t < 4; ++t) {
        int i = tid + t * 256;
        double v = row[i];
        se[i] = v * v;
        si[i] = (unsigned short)i;
        keep[i] = 0;
    }
    __syncthreads();

    for (int ksz = 2; ksz <= 1024; ksz <<= 1) {
        for (int j = ksz >> 1; j > 0; j >>= 1) {
#pragma unroll
            for (int t = 0; t < 4; ++t) {
                int i = tid + t * 256;
                int p = i ^ j;
                if (p > i) {
                    double ei = se[i], ep = se[p];
                    unsigned short ii = si[i], ip = si[p];
                    bool later = !((ei > ep) || (ei == ep && ii < ip));
                    bool dir = ((i & ksz) == 0);
                    if (later == dir) {
                        se[i] = ep; se[p] = ei;
                        si[i] = ip; si[p] = ii;
                    }
                }
            }
            __syncthreads();
        }
    }

    keep[si[tid]] = 1;
    __syncthreads();

#pragma unroll
    for (int t = 0; t < 4; ++t) {
        int i = tid + t * 256;
        float vv = keep[i] ? (float)row[i] : 0.f;
        unsigned short hh = bf16_rne(vv);
        unsigned short ll = bf16_rne(vv - bf16_f32(hh));
        hsplit[(size_t)tok * 2048 + i]        = hh;
        hsplit[(size_t)tok * 2048 + 1024 + i] = ll;
    }
}

// ---------------------------------------------------------------------------
// Memory schedule (ws = 384 MiB, d_out = 128 MiB). Split tensors are 128 MiB
// each ([64Ki][2*512] u16); hF is 256 MiB f32. Timeline per region:
//   ws[  0,128M): S1 (L1->L2) | hF/Hs low half | D2 (dec2->dec3)
//   ws[128,256M): S2 (L2->L3) | hF/Hs high half | D3 (dec3->dec4)
//   ws[256,384M): S3 (L3->L4) | sidecar a64/b64/h64 (pass1->pass2)
//                 | D1 (dec1->dec2) | W3 split (after dec2, ->dec4)
//   d_out: EW0-3,W0,W1,W2 splits + meta (all dead before dec4 writes out)
// Every producer/consumer pair verified temporally disjoint.
// ---------------------------------------------------------------------------
extern "C" void kernel_launch(void* const* d_in, const int* in_sizes, int n_in,
                              void* d_out, int out_size, void* d_ws, size_t ws_size,
                              hipStream_t stream)
{
    (void)n_in; (void)out_size; (void)ws_size;

    const float* x  = (const float*)d_in[0];
    const float* mp = (const float*)d_in[1];

    const float *ew[4], *eb[4], *dw[4], *db[4];
    bool interleaved = (in_sizes[4] == 1024 * 512);
    for (int i = 0; i < 4; ++i) {
        if (interleaved) {
            ew[i] = (const float*)d_in[2 + 4 * i];
            eb[i] = (const float*)d_in[3 + 4 * i];
            dw[i] = (const float*)d_in[4 + 4 * i];
            db[i] = (const float*)d_in[5 + 4 * i];
        } else {
            ew[i] = (const float*)d_in[2 + 2 * i];
            eb[i] = (const float*)d_in[3 + 2 * i];
            dw[i] = (const float*)d_in[10 + 2 * i];
            db[i] = (const float*)d_in[11 + 2 * i];
        }
    }

    char* ws = (char*)d_ws;
    char* ob = (char*)d_out;
    const size_t MB = 1024 * 1024;

    unsigned short* S1 = (unsigned short*)(ws);                // [0,128M)
    unsigned short* S2 = (unsigned short*)(ws + 128 * MB);     // [128,256M)
    unsigned short* S3 = (unsigned short*)(ws + 256 * MB);     // [256,384M)
    float*          hF = (float*)(ws);                         // [0,256M) f32
    unsigned short* Hs = (unsigned short*)(ws);                // [0,256M) split
    unsigned short* D1 = (unsigned short*)(ws + 256 * MB);
    unsigned short* D2 = (unsigned short*)(ws);
    unsigned short* D3 = (unsigned short*)(ws + 128 * MB);
    float*          out = (float*)d_out;

    // weight splits + meta in d_out (all consumed before dec4 writes out)
    unsigned short* p0 = (unsigned short*)ob;
    unsigned short* EW0h = p0 + 0;        unsigned short* EW0l = p0 + 262144;
    unsigned short* EW1h = p0 + 524288;   unsigned short* EW1l = p0 + 786432;
    unsigned short* EW2h = p0 + 1048576;  unsigned short* EW2l = p0 + 1310720;
    unsigned short* EW3h = p0 + 1572864;  unsigned short* EW3l = p0 + 2097152;
    unsigned short* W0h  = p0 + 2621440;  unsigned short* W0l  = p0 + 3145728;
    unsigned short* W1h  = p0 + 3670016;  unsigned short* W1l  = p0 + 3932160;
    unsigned short* W2h  = p0 + 4194304;  unsigned short* W2l  = p0 + 4456448;
    int* meta = (int*)(ob + 16 * MB);

    // W3 split in ws+256M, written AFTER dec2 (D1 dead), read by dec4
    unsigned short* W3h = (unsigned short*)(ws + 256 * MB);
    unsigned short* W3l = W3h + 262144;

    // sidecar fp64 scratch in ws[256,384M) (S3 dead after L4, D1 not yet)
    double* a64 = (double*)(ws + 256 * MB);
    double* b64 = (double*)(ws + 288 * MB);
    double* h64 = (double*)(ws + 320 * MB);

    dim3 blk(256);

    // all weight splits except W3 (d_out region)
    wsplit_t<<<dim3(16, 16), blk, 0, stream>>>(ew[0], EW0h, EW0l, 512, 512);
    wsplit_t<<<dim3(16, 16), blk, 0, stream>>>(ew[1], EW1h, EW1l, 512, 512);
    wsplit_t<<<dim3(16, 16), blk, 0, stream>>>(ew[2], EW2h, EW2l, 512, 512);
    wsplit_t<<<dim3(32, 16), blk, 0, stream>>>(ew[3], EW3h, EW3l, 512, 1024);
    wsplit_t<<<dim3(16, 32), blk, 0, stream>>>(dw[0], W0h,  W0l,  1024, 512);
    wsplit_t<<<dim3(16, 16), blk, 0, stream>>>(dw[1], W1h,  W1l,  512, 512);
    wsplit_t<<<dim3(16, 16), blk, 0, stream>>>(dw[2], W2h,  W2l,  512, 512);
    hipMemsetAsync(meta, 0, sizeof(int), stream);

    // encoder (split-bf16 MFMA): x -> S1 -> S2 -> S3 -> hF
    dim3 ge(4, NTOK / 128), ge4(8, NTOK / 128);
    gemm_u<512, 1, 1, 0><<<ge,  blk, 0, stream>>>(x,  EW0h, EW0l, eb[0], S1, 512,  nullptr);
    gemm_u<512, 1, 1, 1><<<ge,  blk, 0, stream>>>(S1, EW1h, EW1l, eb[1], S2, 512,  nullptr);
    gemm_u<512, 1, 1, 1><<<ge,  blk, 0, stream>>>(S2, EW2h, EW2l, eb[2], S3, 512,  nullptr);
    gemm_u<512, 0, 0, 1><<<ge4, blk, 0, stream>>>(S3, EW3h, EW3l, eb[3], hF, 1024, mp);

    // pass-1 exact-k sparsify (f32 energies, in-place split rewrite)
    topk_pass1<<<dim3(NTOK), blk, 0, stream>>>(hF, Hs, meta);

    // fp64 sidecar, 2 chunks: re-encode uncertain tokens, exact selection
    dim3 g64a(8, UCAP / 64), g64b(16, UCAP / 64);
    for (int c = 0; c < NCHNK; ++c) {
        gather_x<<<dim3(UCAP), blk, 0, stream>>>(x, a64, meta, c);
        gemm_f64<512, 1, 0><<<g64a, blk, 0, stream>>>(a64, ew[0], eb[0], b64, 512,  meta, nullptr, c);
        gemm_f64<512, 1, 0><<<g64a, blk, 0, stream>>>(b64, ew[1], eb[1], a64, 512,  meta, nullptr, c);
        gemm_f64<512, 1, 0><<<g64a, blk, 0, stream>>>(a64, ew[2], eb[2], b64, 512,  meta, nullptr, c);
        gemm_f64<512, 0, 1><<<g64b, blk, 0, stream>>>(b64, ew[3], eb[3], h64, 1024, meta, mp, c);
        topk_pass2<<<dim3(UCAP), blk, 0, stream>>>(h64, Hs, meta, c);
    }

    // decoder (split-bf16 MFMA, pre-split activations)
    dim3 gd(4, NTOK / 128);
    gemm_u<1024, 1, 1, 1><<<gd, blk, 0, stream>>>(Hs, W0h, W0l, db[0], D1, 512, nullptr);
    gemm_u<512, 1, 1, 1><<<gd, blk, 0, stream>>>(D1, W1h, W1l, db[1], D2, 512, nullptr);
    wsplit_t<<<dim3(16, 16), blk, 0, stream>>>(dw[3], W3h, W3l, 512, 512);
    gemm_u<512, 1, 1, 1><<<gd, blk, 0, stream>>>(D2, W2h, W2l, db[2], D3, 512, nullptr);
    gemm_u<512, 0, 0, 1><<<gd, blk, 0, stream>>>(D3, W3h, W3l, db[3], out, 512, nullptr);
}

// Round 6
// 3997.510 us; speedup vs baseline: 1.0006x; 1.0006x over previous
//
#include <hip/hip_runtime.h>

constexpr int NTOK  = 16 * 4096;  // 65536 tokens
constexpr int KSEL  = 256;        // top-k = 2*CDIM
constexpr int UCAP  = 8192;       // sidecar chunk size (fp64 scratch rows)
constexpr int NCHNK = 2;          // sidecar chunks
constexpr int UCAPT = UCAP * NCHNK;

using short8 = __attribute__((ext_vector_type(8))) short;
using ush4   = __attribute__((ext_vector_type(4))) unsigned short;
using f32x4  = __attribute__((ext_vector_type(4))) float;

__device__ inline unsigned short bf16_rne(float x) {
    unsigned u = __float_as_uint(x);
    unsigned r = u + 0x7fffu + ((u >> 16) & 1u);
    return (unsigned short)(r >> 16);
}
__device__ inline float bf16_f32(unsigned short h) {
    return __uint_as_float((unsigned)h << 16);
}

// async global->LDS DMA, 16B per lane; LDS dest = wave-uniform base + lane*16
__device__ inline void gload_lds16(const unsigned short* g, unsigned short* l) {
    __builtin_amdgcn_global_load_lds(
        (const __attribute__((address_space(1))) void*)g,
        (__attribute__((address_space(3))) void*)l, 16, 0, 0);
}

// ---------------------------------------------------------------------------
// Weight split+transpose: W[K][M] fp32 -> WhT/WlT [M][K] bf16 (hi + lo).
// ---------------------------------------------------------------------------
__global__ __launch_bounds__(256)
void wsplit_t(const float* __restrict__ W, unsigned short* __restrict__ WhT,
              unsigned short* __restrict__ WlT, int K, int M)
{
    __shared__ float tile[32][33];
    const int tid = threadIdx.x;
    const int tx = tid & 31, ty = tid >> 5;          // ty 0..7
    const int m0 = blockIdx.x * 32, k0 = blockIdx.y * 32;
#pragma unroll
    for (int i = 0; i < 4; ++i)
        tile[ty + 8 * i][tx] = W[(size_t)(k0 + ty + 8 * i) * M + m0 + tx];
    __syncthreads();
#pragma unroll
    for (int i = 0; i < 4; ++i) {
        int m = ty + 8 * i;
        float v = tile[tx][m];
        unsigned short hh = bf16_rne(v);
        unsigned short ll = bf16_rne(v - bf16_f32(hh));
        WhT[(size_t)(m0 + m) * K + k0 + tx] = hh;
        WlT[(size_t)(m0 + m) * K + k0 + tx] = ll;
    }
}

// ---------------------------------------------------------------------------
// gemm_s: split-bf16 MFMA GEMM with global_load_lds staging and
// conflict-free XOR-swizzled LDS. A must be a pre-split interleaved bf16
// pair [rows][2K] (hi at +0, lo at +K). 3 products (hh + lh + hl).
// LDS layout per array: [128 rows][32 shorts], 16B chunk c stored at
// c ^ ((row>>1)&3). DMA writes linearly; the inverse swizzle is applied to
// the per-lane GLOBAL source address; ds_reads apply the same XOR.
// Bank check: per wave b128 read, each 4-bank group gets exactly 8
// word-accesses -> 8-clk minimum, 2-way only.
// ---------------------------------------------------------------------------
template<int K, int RELU, int OUT_SPLIT>
__global__ __launch_bounds__(256)
void gemm_s(const unsigned short* __restrict__ A,
            const unsigned short* __restrict__ WhT,
            const unsigned short* __restrict__ WlT,
            const float* __restrict__ bias,
            void* Cp, int M, const float* __restrict__ mask)
{
    __shared__ __align__(16) unsigned short sAh[128 * 32];
    __shared__ __align__(16) unsigned short sAl[128 * 32];
    __shared__ __align__(16) unsigned short sBh[128 * 32];
    __shared__ __align__(16) unsigned short sBl[128 * 32];

    const int tid = threadIdx.x;
    const int lane = tid & 63, wid = tid >> 6;
    const int quad = lane >> 4, l16 = lane & 15;

    // XCD-aware block swizzle (nwg % 8 == 0 for all launches here)
    const int gridX = gridDim.x;
    int nwg = gridX * gridDim.y;
    int bid = blockIdx.y * gridX + blockIdx.x;
    int cpx = nwg >> 3;
    int swz = (bid & 7) * cpx + (bid >> 3);
    const int rowBase = (swz / gridX) * 128;
    const int colBase = (swz % gridX) * 128;

    const int wr = (wid & 1) * 64, wc = (wid >> 1) * 64;

    // staging: wave stages rows [wid*32, wid*32+32) of each array,
    // 2 DMA instructions x 16 rows; lane covers (row = +lane/4, chunk = lane&3)
    const int srl = lane >> 2;          // row within 16-row chunk
    const int sq  = lane & 3;           // logical 16B chunk

    f32x4 acc[4][4];
#pragma unroll
    for (int i = 0; i < 4; ++i)
#pragma unroll
        for (int j = 0; j < 4; ++j)
            acc[i][j] = (f32x4){0.f, 0.f, 0.f, 0.f};

    for (int k0 = 0; k0 < K; k0 += 32) {
        __syncthreads();        // previous iteration's reads complete
#pragma unroll
        for (int i16 = 0; i16 < 2; ++i16) {
            const int row = wid * 32 + i16 * 16 + srl;
            const int qs = sq ^ ((row >> 1) & 3);     // inverse swizzle on src
            const unsigned short* gAh = A  + (size_t)(rowBase + row) * (2 * K) + k0 + qs * 8;
            const unsigned short* gBh = WhT + (size_t)(colBase + row) * K + k0 + qs * 8;
            const unsigned short* gBl = WlT + (size_t)(colBase + row) * K + k0 + qs * 8;
            unsigned short* dst = (unsigned short*)0;
            const int dbase = (wid * 32 + i16 * 16) * 32;  // wave-uniform
            gload_lds16(gAh,     &sAh[dbase]);
            gload_lds16(gAh + K, &sAl[dbase]);
            gload_lds16(gBh,     &sBh[dbase]);
            gload_lds16(gBl,     &sBl[dbase]);
            (void)dst;
        }
        asm volatile("s_waitcnt vmcnt(0)" ::: "memory");
        __syncthreads();        // staged tile visible to all waves

        short8 ah[4], al[4], bh[4], bl[4];
#pragma unroll
        for (int t4 = 0; t4 < 4; ++t4) {
            const int ra = wr + t4 * 16 + l16;
            const int rb = wc + t4 * 16 + l16;
            const int ca = (quad ^ ((ra >> 1) & 3)) * 8;
            const int cb = (quad ^ ((rb >> 1) & 3)) * 8;
            ah[t4] = *(const short8*)&sAh[ra * 32 + ca];
            al[t4] = *(const short8*)&sAl[ra * 32 + ca];
            bh[t4] = *(const short8*)&sBh[rb * 32 + cb];
            bl[t4] = *(const short8*)&sBl[rb * 32 + cb];
        }
#pragma unroll
        for (int rt = 0; rt < 4; ++rt)
#pragma unroll
            for (int ct = 0; ct < 4; ++ct) {
                acc[rt][ct] = __builtin_amdgcn_mfma_f32_16x16x32_bf16(ah[rt], bh[ct], acc[rt][ct], 0, 0, 0);
                acc[rt][ct] = __builtin_amdgcn_mfma_f32_16x16x32_bf16(al[rt], bh[ct], acc[rt][ct], 0, 0, 0);
                acc[rt][ct] = __builtin_amdgcn_mfma_f32_16x16x32_bf16(ah[rt], bl[ct], acc[rt][ct], 0, 0, 0);
            }
    }

#pragma unroll
    for (int ct = 0; ct < 4; ++ct) {
        int col = colBase + wc + ct * 16 + l16;
        float bc = bias[col];
#pragma unroll
        for (int rt = 0; rt < 4; ++rt)
#pragma unroll
            for (int r = 0; r < 4; ++r) {
                int row = rowBase + wr + rt * 16 + quad * 4 + r;
                float v = acc[rt][ct][r] + bc;
                if (RELU) v = fmaxf(v, 0.f);
                if (mask) { if (mask[(size_t)row * M + col] > 0.f) v = 0.f; }
                if constexpr (OUT_SPLIT) {
                    unsigned short* Cs = (unsigned short*)Cp;
                    unsigned short hh = bf16_rne(v);
                    unsigned short ll = bf16_rne(v - bf16_f32(hh));
                    Cs[(size_t)row * (2 * M) + col]     = hh;
                    Cs[(size_t)row * (2 * M) + M + col] = ll;
                } else {
                    ((float*)Cp)[(size_t)row * M + col] = v;
                }
            }
    }
}

// ---------------------------------------------------------------------------
// gemm_u (layer-1 only): A is f32, split on the fly. Proven R5 path.
// ---------------------------------------------------------------------------
template<int K, int RELU, int OUT_SPLIT>
__global__ __launch_bounds__(256)
void gemm_u(const float* __restrict__ Af, const unsigned short* __restrict__ WhT,
            const unsigned short* __restrict__ WlT, const float* __restrict__ bias,
            void* Cp, int M, const float* __restrict__ mask)
{
    __shared__ __align__(16) unsigned short sAh[128 * 40];
    __shared__ __align__(16) unsigned short sAl[128 * 40];
    __shared__ __align__(16) unsigned short sBh[128 * 40];
    __shared__ __align__(16) unsigned short sBl[128 * 40];

    const int tid = threadIdx.x;
    const int lane = tid & 63, wid = tid >> 6;
    const int quad = lane >> 4, l16 = lane & 15;

    const int gridX = gridDim.x;
    int nwg = gridX * gridDim.y;
    int bid = blockIdx.y * gridX + blockIdx.x;
    int cpx = nwg >> 3;
    int swz = (bid & 7) * cpx + (bid >> 3);
    const int rowBase = (swz / gridX) * 128;
    const int colBase = (swz % gridX) * 128;

    const int wr = (wid & 1) * 64, wc = (wid >> 1) * 64;
    const int sr = tid >> 1;
    const int sk = (tid & 1) * 16;

    f32x4 acc[4][4];
#pragma unroll
    for (int i = 0; i < 4; ++i)
#pragma unroll
        for (int j = 0; j < 4; ++j)
            acc[i][j] = (f32x4){0.f, 0.f, 0.f, 0.f};

    for (int k0 = 0; k0 < K; k0 += 32) {
        const float* ap = &Af[(size_t)(rowBase + sr) * K + k0 + sk];
        float4 a0 = *(const float4*)ap;
        float4 a1 = *(const float4*)(ap + 4);
        float4 a2 = *(const float4*)(ap + 8);
        float4 a3 = *(const float4*)(ap + 12);
        const unsigned short* whp = &WhT[(size_t)(colBase + sr) * K + k0 + sk];
        const unsigned short* wlp = &WlT[(size_t)(colBase + sr) * K + k0 + sk];
        short8 wh0 = *(const short8*)whp;
        short8 wh1 = *(const short8*)(whp + 8);
        short8 wl0 = *(const short8*)wlp;
        short8 wl1 = *(const short8*)(wlp + 8);

        float f[16] = {a0.x, a0.y, a0.z, a0.w, a1.x, a1.y, a1.z, a1.w,
                       a2.x, a2.y, a2.z, a2.w, a3.x, a3.y, a3.z, a3.w};
        unsigned short __align__(16) hs[16], ls[16];
#pragma unroll
        for (int j = 0; j < 16; ++j) {
            hs[j] = bf16_rne(f[j]);
            ls[j] = bf16_rne(f[j] - bf16_f32(hs[j]));
        }

        __syncthreads();
        *(short8*)&sAh[sr * 40 + sk]     = *(short8*)&hs[0];
        *(short8*)&sAh[sr * 40 + sk + 8] = *(short8*)&hs[8];
        *(short8*)&sAl[sr * 40 + sk]     = *(short8*)&ls[0];
        *(short8*)&sAl[sr * 40 + sk + 8] = *(short8*)&ls[8];
        *(short8*)&sBh[sr * 40 + sk]     = wh0;
        *(short8*)&sBh[sr * 40 + sk + 8] = wh1;
        *(short8*)&sBl[sr * 40 + sk]     = wl0;
        *(short8*)&sBl[sr * 40 + sk + 8] = wl1;
        __syncthreads();

        short8 ah[4], al[4], bh[4], bl[4];
#pragma unroll
        for (int t4 = 0; t4 < 4; ++t4) {
            ah[t4] = *(const short8*)&sAh[(wr + t4 * 16 + l16) * 40 + quad * 8];
            al[t4] = *(const short8*)&sAl[(wr + t4 * 16 + l16) * 40 + quad * 8];
            bh[t4] = *(const short8*)&sBh[(wc + t4 * 16 + l16) * 40 + quad * 8];
            bl[t4] = *(const short8*)&sBl[(wc + t4 * 16 + l16) * 40 + quad * 8];
        }
#pragma unroll
        for (int rt = 0; rt < 4; ++rt)
#pragma unroll
            for (int ct = 0; ct < 4; ++ct) {
                acc[rt][ct] = __builtin_amdgcn_mfma_f32_16x16x32_bf16(ah[rt], bh[ct], acc[rt][ct], 0, 0, 0);
                acc[rt][ct] = __builtin_amdgcn_mfma_f32_16x16x32_bf16(al[rt], bh[ct], acc[rt][ct], 0, 0, 0);
                acc[rt][ct] = __builtin_amdgcn_mfma_f32_16x16x32_bf16(ah[rt], bl[ct], acc[rt][ct], 0, 0, 0);
            }
    }

#pragma unroll
    for (int ct = 0; ct < 4; ++ct) {
        int col = colBase + wc + ct * 16 + l16;
        float bc = bias[col];
#pragma unroll
        for (int rt = 0; rt < 4; ++rt)
#pragma unroll
            for (int r = 0; r < 4; ++r) {
                int row = rowBase + wr + rt * 16 + quad * 4 + r;
                float v = acc[rt][ct][r] + bc;
                if (RELU) v = fmaxf(v, 0.f);
                if (mask) { if (mask[(size_t)row * M + col] > 0.f) v = 0.f; }
                if constexpr (OUT_SPLIT) {
                    unsigned short* Cs = (unsigned short*)Cp;
                    unsigned short hh = bf16_rne(v);
                    unsigned short ll = bf16_rne(v - bf16_f32(hh));
                    Cs[(size_t)row * (2 * M) + col]     = hh;
                    Cs[(size_t)row * (2 * M) + M + col] = ll;
                } else {
                    ((float*)Cp)[(size_t)row * M + col] = v;
                }
            }
    }
}

// ---------------------------------------------------------------------------
// Pass-1 topk: exact-k radix select on f32 energies + boundary-gap
// detection (uncertain tokens -> meta for fp64 redo). Reads f32 h, rewrites
// in place as interleaved bf16 hi/lo pair [t][2048].
// ---------------------------------------------------------------------------
__global__ __launch_bounds__(256)
void topk_pass1(const float* h, unsigned short* hsplit, int* __restrict__ meta)
{
    const int t = blockIdx.x, tid = threadIdx.x;
    const int lane = tid & 63, wid = tid >> 6;

    __shared__ unsigned hist[256];
    __shared__ unsigned wsum[4];
    __shared__ unsigned dmx[4];
    __shared__ unsigned s_prefix;
    __shared__ int s_need;

    float4 hv = ((const float4*)(h + (size_t)t * 1024))[tid];
    float v[4] = {hv.x, hv.y, hv.z, hv.w};
    unsigned u[4];
#pragma unroll
    for (int j = 0; j < 4; ++j) u[j] = __float_as_uint(v[j] * v[j]);

    if (tid == 0) { s_prefix = 0u; s_need = KSEL; }
    __syncthreads();

    for (int p = 3; p >= 0; --p) {
        unsigned pref = s_prefix;
        int need = s_need;
        hist[tid] = 0u;
        __syncthreads();
#pragma unroll
        for (int j = 0; j < 4; ++j) {
            bool match = (p == 3) || ((u[j] >> (8 * (p + 1))) == (pref >> (8 * (p + 1))));
            if (match) atomicAdd(&hist[(u[j] >> (8 * p)) & 255u], 1u);
        }
        __syncthreads();
        unsigned x = hist[tid];
        unsigned s = x;
#pragma unroll
        for (int off = 1; off < 64; off <<= 1) {
            unsigned o = __shfl_down(s, off);
            if (lane + off < 64) s += o;
        }
        if (lane == 0) wsum[wid] = s;
        __syncthreads();
        unsigned above = 0;
        for (int w = wid + 1; w < 4; ++w) above += wsum[w];
        unsigned incl = s + above;
        unsigned excl = incl - x;
        if (incl >= (unsigned)need && excl < (unsigned)need) {
            s_prefix = pref | ((unsigned)tid << (8 * p));
            s_need = need - (int)excl;
        }
        __syncthreads();
    }
    const unsigned tau = s_prefix;

    unsigned cg = 0, ce = 0;
#pragma unroll
    for (int j = 0; j < 4; ++j) {
        cg += (u[j] > tau) ? 1u : 0u;
        ce += (u[j] == tau) ? 1u : 0u;
    }
    unsigned packed = (cg << 16) | ce;
    unsigned ps = packed;
#pragma unroll
    for (int off = 1; off < 64; off <<= 1) {
        unsigned o = __shfl_up(ps, off);
        if (lane >= off) ps += o;
    }
    if (lane == 63) wsum[wid] = ps;
    __syncthreads();
    unsigned below = 0;
    for (int w = 0; w < wid; ++w) below += wsum[w];
    unsigned total = wsum[0] + wsum[1] + wsum[2] + wsum[3];
    unsigned incl = ps + below;
    int need_eq = KSEL - (int)(total >> 16);
    int eq_base = (int)((incl - packed) & 0xffffu);

    bool kp[4];
    {
        int r = 0;
#pragma unroll
        for (int j = 0; j < 4; ++j) {
            if (u[j] > tau) kp[j] = true;
            else if (u[j] == tau) { kp[j] = (eq_base + r) < need_eq; ++r; }
            else kp[j] = false;
        }
    }

    unsigned dmax = 0;
#pragma unroll
    for (int j = 0; j < 4; ++j) if (!kp[j] && u[j] > dmax) dmax = u[j];
#pragma unroll
    for (int off = 32; off > 0; off >>= 1) {
        unsigned o = __shfl_xor(dmax, off);
        if (o > dmax) dmax = o;
    }
    if (lane == 0) dmx[wid] = dmax;
    __syncthreads();
    if (tid == 0) {
        unsigned lo = dmx[0];
        for (int w = 1; w < 4; ++w) if (dmx[w] > lo) lo = dmx[w];
        float tauf = __uint_as_float(tau);
        float lof  = __uint_as_float(lo);
        if (tauf - lof <= fmaf(tauf, 4e-4f, 4e-5f)) {
            int slot = atomicAdd(&meta[0], 1);
            if (slot < UCAPT) meta[1 + slot] = t;
        }
    }

    unsigned short hs[4], ls[4];
#pragma unroll
    for (int j = 0; j < 4; ++j) {
        float ov = kp[j] ? v[j] : 0.f;
        hs[j] = bf16_rne(ov);
        ls[j] = bf16_rne(ov - bf16_f32(hs[j]));
    }
    size_t base = (size_t)t * 2048 + 4 * tid;
    *(ush4*)&hsplit[base]        = (ush4){hs[0], hs[1], hs[2], hs[3]};
    *(ush4*)&hsplit[base + 1024] = (ush4){ls[0], ls[1], ls[2], ls[3]};
}

// ---------------------------------------------------------------------------
// fp64 sidecar (chunked): gather x rows for uncertain tokens of one chunk.
// ---------------------------------------------------------------------------
__global__ __launch_bounds__(256)
void gather_x(const float* __restrict__ x, double* __restrict__ a64,
              const int* __restrict__ meta, int chunk)
{
    int cnt = meta[0]; if (cnt > UCAPT) cnt = UCAPT;
    int g = chunk * UCAP + blockIdx.x;
    if (g >= cnt) return;
    int tok = meta[1 + g];
    const float* src = &x[(size_t)tok * 512];
    double* dst = &a64[(size_t)blockIdx.x * 512];
    for (int i = threadIdx.x; i < 512; i += 256) dst[i] = (double)src[i];
}

// ---------------------------------------------------------------------------
// fp64 GEMM over one sidecar chunk. 64x64 tile, 256 threads, 4x4/thr.
// ---------------------------------------------------------------------------
template<int K, int RELU, int MASKED>
__global__ __launch_bounds__(256)
void gemm_f64(const double* __restrict__ A, const float* __restrict__ W,
              const float* __restrict__ bias, double* __restrict__ Cd,
              int M, const int* __restrict__ meta, const float* __restrict__ mp,
              int chunk)
{
    int cnt = meta[0]; if (cnt > UCAPT) cnt = UCAPT;
    int cloc = cnt - chunk * UCAP;
    if (cloc < 0) cloc = 0; if (cloc > UCAP) cloc = UCAP;
    const int rowBase = blockIdx.y * 64;
    if (rowBase >= cloc) return;
    const int colBase = blockIdx.x * 64;

    __shared__ double sA[16][65];
    __shared__ double sW[16][65];
    const int tid = threadIdx.x;
    const int tx = tid & 15, ty = tid >> 4;
    const int lr = tid & 63;
    const int lk4 = (tid >> 6) * 4;
    const int wk = tid >> 4;
    const int wc = (tid & 15) * 4;

    double acc[4][4] = {};

    for (int k0 = 0; k0 < K; k0 += 16) {
        const double* ap = &A[(size_t)(rowBase + lr) * K + k0 + lk4];
        double a0 = ap[0], a1 = ap[1], a2 = ap[2], a3 = ap[3];
        float4 wv = *(const float4*)&W[(size_t)(k0 + wk) * M + colBase + wc];
        __syncthreads();
        sA[lk4 + 0][lr] = a0; sA[lk4 + 1][lr] = a1;
        sA[lk4 + 2][lr] = a2; sA[lk4 + 3][lr] = a3;
        sW[wk][wc + 0] = (double)wv.x; sW[wk][wc + 1] = (double)wv.y;
        sW[wk][wc + 2] = (double)wv.z; sW[wk][wc + 3] = (double)wv.w;
        __syncthreads();
#pragma unroll
        for (int k = 0; k < 16; ++k) {
            double av[4], wl[4];
#pragma unroll
            for (int i = 0; i < 4; ++i) av[i] = sA[k][ty * 4 + i];
#pragma unroll
            for (int i = 0; i < 4; ++i) wl[i] = sW[k][tx * 4 + i];
#pragma unroll
            for (int a = 0; a < 4; ++a)
#pragma unroll
                for (int b = 0; b < 4; ++b)
                    acc[a][b] = fma(av[a], wl[b], acc[a][b]);
        }
    }

#pragma unroll
    for (int a = 0; a < 4; ++a) {
        int row = rowBase + ty * 4 + a;
        if (row >= cloc) continue;
        int tok = MASKED ? meta[1 + chunk * UCAP + row] : 0;
#pragma unroll
        for (int b = 0; b < 4; ++b) {
            int col = colBase + tx * 4 + b;
            double vv = acc[a][b] + (double)bias[col];
            if (RELU) vv = vv > 0.0 ? vv : 0.0;
            if (MASKED) { if (mp[(size_t)tok * 1024 + col] > 0.f) vv = 0.0; }
            Cd[(size_t)row * M + col] = vv;
        }
    }
}

// ---------------------------------------------------------------------------
// Pass-2 topk for uncertain tokens of one chunk: exact fp64 energies,
// bitonic sort (energy desc, idx asc), keep ranks < 256; scatter masked
// interleaved bf16 hi/lo rows into hsplit.
// ---------------------------------------------------------------------------
__global__ __launch_bounds__(256)
void topk_pass2(const double* __restrict__ h64, unsigned short* __restrict__ hsplit,
                const int* __restrict__ meta, int chunk)
{
    int cnt = meta[0]; if (cnt > UCAPT) cnt = UCAPT;
    int g = chunk * UCAP + blockIdx.x;
    if (g >= cnt) return;
    int tok = meta[1 + g];

    __shared__ double se[1024];
    __shared__ unsigned short si[1024];
    __shared__ unsigned char keep[1024];
    const int tid = threadIdx.x;
    const double* row = &h64[(size_t)blockIdx.x * 1024];

#pragma unroll
    for (int t = 0; t < 4; ++t) {
        int i = tid + t * 256;
        double v = row[i];
        se[i] = v * v;
        si[i] = (unsigned short)i;
        keep[i] = 0;
    }
    __syncthreads();

    for (int ksz = 2; ksz <= 1024; ksz <<= 1) {
        for (int j = ksz >> 1; j > 0; j >>= 1) {
#pragma unroll
            for (int t = 0; t < 4; ++t) {
                int i = tid + t * 256;
                int p = i ^ j;
                if (p > i) {
                    double ei = se[i], ep = se[p];
                    unsigned short ii = si[i], ip = si[p];
                    bool later = !((ei > ep) || (ei == ep && ii < ip));
                    bool dir = ((i & ksz) == 0);
                    if (later == dir) {
                        se[i] = ep; se[p] = ei;
                        si[i] = ip; si[p] = ii;
                    }
                }
            }
            __syncthreads();
        }
    }

    keep[si[tid]] = 1;
    __syncthreads();

#pragma unroll
    for (int t = 0; t < 4; ++t) {
        int i = tid + t * 256;
        float vv = keep[i] ? (float)row[i] : 0.f;
        unsigned short hh = bf16_rne(vv);
        unsigned short ll = bf16_rne(vv - bf16_f32(hh));
        hsplit[(size_t)tok * 2048 + i]        = hh;
        hsplit[(size_t)tok * 2048 + 1024 + i] = ll;
    }
}

// ---------------------------------------------------------------------------
// Memory schedule identical to R5 (verified passing):
//   ws[  0,128M): S1 | hF/Hs low | D2      ws[128,256M): S2 | hF/Hs high | D3
//   ws[256,384M): S3 | sidecar a64/b64/h64 | D1 | W3 split (after dec2)
//   d_out: EW0-3, W0, W1, W2 splits + meta (dead before dec4 writes out)
// ---------------------------------------------------------------------------
extern "C" void kernel_launch(void* const* d_in, const int* in_sizes, int n_in,
                              void* d_out, int out_size, void* d_ws, size_t ws_size,
                              hipStream_t stream)
{
    (void)n_in; (void)out_size; (void)ws_size;

    const float* x  = (const float*)d_in[0];
    const float* mp = (const float*)d_in[1];

    const float *ew[4], *eb[4], *dw[4], *db[4];
    bool interleaved = (in_sizes[4] == 1024 * 512);
    for (int i = 0; i < 4; ++i) {
        if (interleaved) {
            ew[i] = (const float*)d_in[2 + 4 * i];
            eb[i] = (const float*)d_in[3 + 4 * i];
            dw[i] = (const float*)d_in[4 + 4 * i];
            db[i] = (const float*)d_in[5 + 4 * i];
        } else {
            ew[i] = (const float*)d_in[2 + 2 * i];
            eb[i] = (const float*)d_in[3 + 2 * i];
            dw[i] = (const float*)d_in[10 + 2 * i];
            db[i] = (const float*)d_in[11 + 2 * i];
        }
    }

    char* ws = (char*)d_ws;
    char* ob = (char*)d_out;
    const size_t MB = 1024 * 1024;

    unsigned short* S1 = (unsigned short*)(ws);
    unsigned short* S2 = (unsigned short*)(ws + 128 * MB);
    unsigned short* S3 = (unsigned short*)(ws + 256 * MB);
    float*          hF = (float*)(ws);
    unsigned short* Hs = (unsigned short*)(ws);
    unsigned short* D1 = (unsigned short*)(ws + 256 * MB);
    unsigned short* D2 = (unsigned short*)(ws);
    unsigned short* D3 = (unsigned short*)(ws + 128 * MB);
    float*          out = (float*)d_out;

    unsigned short* p0 = (unsigned short*)ob;
    unsigned short* EW0h = p0 + 0;        unsigned short* EW0l = p0 + 262144;
    unsigned short* EW1h = p0 + 524288;   unsigned short* EW1l = p0 + 786432;
    unsigned short* EW2h = p0 + 1048576;  unsigned short* EW2l = p0 + 1310720;
    unsigned short* EW3h = p0 + 1572864;  unsigned short* EW3l = p0 + 2097152;
    unsigned short* W0h  = p0 + 2621440;  unsigned short* W0l  = p0 + 3145728;
    unsigned short* W1h  = p0 + 3670016;  unsigned short* W1l  = p0 + 3932160;
    unsigned short* W2h  = p0 + 4194304;  unsigned short* W2l  = p0 + 4456448;
    int* meta = (int*)(ob + 16 * MB);

    unsigned short* W3h = (unsigned short*)(ws + 256 * MB);
    unsigned short* W3l = W3h + 262144;

    double* a64 = (double*)(ws + 256 * MB);
    double* b64 = (double*)(ws + 288 * MB);
    double* h64 = (double*)(ws + 320 * MB);

    dim3 blk(256);

    wsplit_t<<<dim3(16, 16), blk, 0, stream>>>(ew[0], EW0h, EW0l, 512, 512);
    wsplit_t<<<dim3(16, 16), blk, 0, stream>>>(ew[1], EW1h, EW1l, 512, 512);
    wsplit_t<<<dim3(16, 16), blk, 0, stream>>>(ew[2], EW2h, EW2l, 512, 512);
    wsplit_t<<<dim3(32, 16), blk, 0, stream>>>(ew[3], EW3h, EW3l, 512, 1024);
    wsplit_t<<<dim3(16, 32), blk, 0, stream>>>(dw[0], W0h,  W0l,  1024, 512);
    wsplit_t<<<dim3(16, 16), blk, 0, stream>>>(dw[1], W1h,  W1l,  512, 512);
    wsplit_t<<<dim3(16, 16), blk, 0, stream>>>(dw[2], W2h,  W2l,  512, 512);
    hipMemsetAsync(meta, 0, sizeof(int), stream);

    // encoder: x -> S1 (reg-staged L1) -> S2 -> S3 -> hF (gemm_s)
    dim3 ge(4, NTOK / 128), ge4(8, NTOK / 128);
    gemm_u<512, 1, 1><<<ge,  blk, 0, stream>>>(x,  EW0h, EW0l, eb[0], S1, 512,  nullptr);
    gemm_s<512, 1, 1><<<ge,  blk, 0, stream>>>(S1, EW1h, EW1l, eb[1], S2, 512,  nullptr);
    gemm_s<512, 1, 1><<<ge,  blk, 0, stream>>>(S2, EW2h, EW2l, eb[2], S3, 512,  nullptr);
    gemm_s<512, 0, 0><<<ge4, blk, 0, stream>>>(S3, EW3h, EW3l, eb[3], hF, 1024, mp);

    // pass-1 exact-k sparsify (f32 energies, in-place split rewrite)
    topk_pass1<<<dim3(NTOK), blk, 0, stream>>>(hF, Hs, meta);

    // fp64 sidecar, 2 chunks
    dim3 g64a(8, UCAP / 64), g64b(16, UCAP / 64);
    for (int c = 0; c < NCHNK; ++c) {
        gather_x<<<dim3(UCAP), blk, 0, stream>>>(x, a64, meta, c);
        gemm_f64<512, 1, 0><<<g64a, blk, 0, stream>>>(a64, ew[0], eb[0], b64, 512,  meta, nullptr, c);
        gemm_f64<512, 1, 0><<<g64a, blk, 0, stream>>>(b64, ew[1], eb[1], a64, 512,  meta, nullptr, c);
        gemm_f64<512, 1, 0><<<g64a, blk, 0, stream>>>(a64, ew[2], eb[2], b64, 512,  meta, nullptr, c);
        gemm_f64<512, 0, 1><<<g64b, blk, 0, stream>>>(b64, ew[3], eb[3], h64, 1024, meta, mp, c);
        topk_pass2<<<dim3(UCAP), blk, 0, stream>>>(h64, Hs, meta, c);
    }

    // decoder (gemm_s, pre-split activations)
    dim3 gd(4, NTOK / 128);
    gemm_s<1024, 1, 1><<<gd, blk, 0, stream>>>(Hs, W0h, W0l, db[0], D1, 512, nullptr);
    gemm_s<512, 1, 1><<<gd, blk, 0, stream>>>(D1, W1h, W1l, db[1], D2, 512, nullptr);
    wsplit_t<<<dim3(16, 16), blk, 0, stream>>>(dw[3], W3h, W3l, 512, 512);
    gemm_s<512, 1, 1><<<gd, blk, 0, stream>>>(D2, W2h, W2l, db[2], D3, 512, nullptr);
    gemm_s<512, 0, 0><<<gd, blk, 0, stream>>>(D3, W3h, W3l, db[3], out, 512, nullptr);
}